// Round 4
// baseline (344.157 us; speedup 1.0000x reference)
//
#include <hip/hip_runtime.h>

#define DIM   4096
#define KVDIM 1024   // n_kv_heads * head_dim
#define NB    8      // batch
#define TOTAL 16384
#define BCAST_BLOCKS 8192   // 2 rows per block

// x[b*KVDIM + j] = dot(emb[b,:], W_up[j,:])  -- one wave per (j,b), unrolled x16
__global__ __launch_bounds__(256)
void k_up(const float* __restrict__ emb, const float* __restrict__ wup,
          float* __restrict__ x) {
    int wid  = blockIdx.x * 4 + (threadIdx.x >> 6);
    int lane = threadIdx.x & 63;
    int j = wid >> 3;      // 0..1023 (b inner: 8 consecutive waves share one W_up row)
    int b = wid & 7;
    const float4* e = (const float4*)(emb + b * DIM);
    const float4* w = (const float4*)(wup + (long)j * DIM);
    float acc = 0.f;
    #pragma unroll
    for (int ii = 0; ii < 16; ii++) {
        int it = ii * 64 + lane;
        float4 ev = e[it], wv = w[it];
        acc += ev.x * wv.x + ev.y * wv.y + ev.z * wv.z + ev.w * wv.w;
    }
    #pragma unroll
    for (int off = 32; off; off >>= 1) acc += __shfl_down(acc, off, 64);
    if (lane == 0) x[b * KVDIM + j] = acc;
}

// y[b*DIM + o] = dot(val[b,:], W_down[o,:]),  val[b,k] = x[b,(k>>9)*128 + (k&127)]
// One o per block, K split across 4 waves. All 4 W_down loads hoisted up front
// (single HBM-latency exposure), then 32 L2-hot x loads + FMAs.
__global__ __launch_bounds__(256)
void k_down(const float* __restrict__ x, const float* __restrict__ wdn,
            float* __restrict__ y) {
    __shared__ float part[4][NB];
    int o    = blockIdx.x;            // 0..4095
    int wv   = threadIdx.x >> 6;      // K-quarter
    int lane = threadIdx.x & 63;
    const float4* w = (const float4*)(wdn + (long)o * DIM);

    // hoisted W_down loads: 4 float4 in flight before any use
    float4 wr[4];
    int kvi[4];
    #pragma unroll
    for (int ii = 0; ii < 4; ii++) {
        int it = wv * 256 + ii * 64 + lane;
        wr[ii] = w[it];
        int k0 = it * 4;
        kvi[ii] = ((k0 >> 9) << 7) + (k0 & 127);   // 16B-aligned gather index
    }

    float acc[NB];
    #pragma unroll
    for (int b = 0; b < NB; b++) acc[b] = 0.f;
    #pragma unroll
    for (int ii = 0; ii < 4; ii++) {
        float4 wvv = wr[ii];
        #pragma unroll
        for (int b = 0; b < NB; b++) {
            const float4 xv = *(const float4*)(x + b * KVDIM + kvi[ii]);
            acc[b] += xv.x * wvv.x + xv.y * wvv.y + xv.z * wvv.z + xv.w * wvv.w;
        }
    }
    #pragma unroll
    for (int b = 0; b < NB; b++) {
        #pragma unroll
        for (int off = 32; off; off >>= 1) acc[b] += __shfl_down(acc[b], off, 64);
    }
    if (lane == 0) {
        #pragma unroll
        for (int b = 0; b < NB; b++) part[wv][b] = acc[b];
    }
    __syncthreads();
    if (threadIdx.x < NB) {
        int b = threadIdx.x;
        y[b * DIM + o] = part[0][b] + part[1][b] + part[2][b] + part[3][b];
    }
}

// out[row,:] = y[seq_id(row),:]  -- 2 rows per block, plain float4 stores.
__global__ __launch_bounds__(256)
void k_bcast(const float* __restrict__ y, const int* __restrict__ seqlen,
             float4* __restrict__ out) {
    int c0 = seqlen[0];
    int c1 = c0 + seqlen[1];
    int c2 = c1 + seqlen[2];
    int c3 = c2 + seqlen[3];
    int c4 = c3 + seqlen[4];
    int c5 = c4 + seqlen[5];
    int c6 = c5 + seqlen[6];
    #pragma unroll
    for (int g = 0; g < TOTAL / BCAST_BLOCKS; g++) {
        int row = blockIdx.x + g * BCAST_BLOCKS;
        int s = (row >= c0) + (row >= c1) + (row >= c2) + (row >= c3)
              + (row >= c4) + (row >= c5) + (row >= c6);
        const float4* yr = (const float4*)(y + s * DIM);
        float4* orow = out + (long)row * (DIM / 4);
        #pragma unroll
        for (int c = threadIdx.x; c < DIM / 4; c += 256)
            orow[c] = yr[c];
    }
}

extern "C" void kernel_launch(void* const* d_in, const int* in_sizes, int n_in,
                              void* d_out, int out_size, void* d_ws, size_t ws_size,
                              hipStream_t stream) {
    const float* emb = (const float*)d_in[0];
    const float* wup = (const float*)d_in[1];
    const float* wdn = (const float*)d_in[2];
    const int* seqlen = (const int*)d_in[3];

    float* x = (float*)d_ws;           // 8*1024 fp32 = 32 KB
    float* y = x + NB * KVDIM;         // 8*4096 fp32 = 128 KB

    k_up   <<<NB * KVDIM / 4, 256, 0, stream>>>(emb, wup, x);
    k_down <<<DIM,            256, 0, stream>>>(x, wdn, y);
    k_bcast<<<BCAST_BLOCKS,   256, 0, stream>>>(y, seqlen, (float4*)d_out);
}